// Round 7
// baseline (3866.131 us; speedup 1.0000x reference)
//
#include <hip/hip_runtime.h>

// ---------------------------------------------------------------------------
// STFT-Fourier-KAN DGCNN on MI355X.
// R5+R6 benches were infra failures (container acquisition died before the
// kernel ran) — resubmitting unchanged for a measurement.
// R4 result: absmax 0.0586 vs 0.0522 — residual fully explained by bf16
// rounding of MFMA operands (budget matched measurement).
// This kernel: MFMA operands + h2 in fp16 (4x less rounding, same MFMA rate,
// same fragment layout). Activations fp32; layer 4 fully fp32; kNN exact
// fp32. Predicted absmax ~0.01.
// ---------------------------------------------------------------------------

typedef unsigned short u16;
typedef unsigned int   u32;
typedef __attribute__((ext_vector_type(8))) _Float16 half8;
typedef __attribute__((ext_vector_type(4))) float f32x4;

__device__ __forceinline__ float bf2f(u16 u) {
  u32 v = ((u32)u) << 16;
  return __uint_as_float(v);
}
__device__ __forceinline__ u16 f2bfr(float f) {  // bf16 round-to-nearest-even
  u32 x = __float_as_uint(f);
  u32 r = x + 0x7FFFu + ((x >> 16) & 1u);
  return (u16)(r >> 16);
}
__device__ __forceinline__ u16 f2h(float f) {    // fp16 RTN bits
  _Float16 h = (_Float16)f;
  u16 r;
  __builtin_memcpy(&r, &h, 2);
  return r;
}
__device__ __forceinline__ float h2f(u16 u) {
  _Float16 h;
  __builtin_memcpy(&h, &u, 2);
  return (float)h;
}
// dtype-dispatched external load (flag wave-uniform -> scalar branch)
__device__ __forceinline__ float ldf(const void* p, size_t i, bool f32) {
  return f32 ? ((const float*)p)[i] : bf2f(((const u16*)p)[i]);
}

// ---------------- workspace layout (bytes) ----------------
#define NBR_OFF   ((size_t)0)                       // int32 [163840]       655,360
#define FLAG_OFF  ((size_t)917504)                  // int32 [1]
#define XG_OFF    ((size_t)(1u << 20))              // f32 [8][2048]         65,536
#define L4P_OFF   (((size_t)(1u << 20)) + 131072)   // f32 [8][15][240]     115,200
#define C1T_OFF   (((size_t)(1u << 20)) + 524288)   // fp16 [64][64]          8,192
#define C2T_OFF   (((size_t)(1u << 20)) + 589824)   // fp16 [128][1120]     286,720
#define C3T_OFF   ((size_t)(2u << 20))              // fp16 [1024][2240]  4,587,520
#define C4T_OFF   ((size_t)(7u << 20))              // f32  [40][38400]   6,144,000
#define X1_OFF    ((size_t)(14u << 20))             // f32 [8192][128]    4,194,304
#define H1_OFF    ((size_t)(19u << 20))             // f32 [163840][64]  41,943,040
#define X_OFF     ((size_t)(19u << 20))             // f32 [8192][1024]  (overlaps dead h1)
#define H2_OFF    ((size_t)(61u << 20))             // fp16 [163840][128] 41,943,040
// peak ~103 MB

// ---------------- dtype detector -------------------------------------------
__global__ void detect_kernel(const void* __restrict__ pos,
                              int* __restrict__ flag) {
  int t = threadIdx.x;  // 64 threads
  float a = fabsf(((const float*)pos)[t]);
  bool ok = (a > 1.0e-3f && a < 100.0f);
  unsigned long long m = __ballot(ok);
  if (t == 0) *flag = (__popcll(m) >= 32) ? 1 : 0;  // 1 = fp32 externals
}

// ---------------- coeff transpose: c[part][o][w][i][g] -> ct[o][f] ----------
// f = ((w*W+i)*5 + g)*2 + part ; pad f>=Kt with zeros (layer1 pads 60->64)
// outf32: write fp32 (layer 4) else fp16 bits
__global__ void tkan_kernel(const void* __restrict__ src, void* __restrict__ dst,
                            int dout, int nw, int W, int total, int KPAD,
                            int outf32, const int* __restrict__ dfl) {
  int id = blockIdx.x * 256 + threadIdx.x;
  if (id >= total) return;
  const bool f32 = (*dfl != 0);
  int o = id / KPAD, f = id % KPAD;
  int Kt = nw * W * 10;
  float v = 0.f;
  if (f < Kt) {
    int part = f & 1, q = f >> 1;
    int gg = q % 5, a2 = q / 5;
    int i = a2 % W, w = a2 / W;
    int OS = nw * W * 5;
    size_t sidx = (size_t)part * (dout * OS) + (size_t)o * OS + w * (W * 5) + i * 5 + gg;
    v = ldf(src, sidx, f32);
  }
  if (outf32) ((float*)dst)[id] = v;
  else        ((u16*)dst)[id] = f2h(v);
}

// ---------------- brute-force kNN, stable top-20 (matches lax.top_k) --------
__global__ __launch_bounds__(256) void knn_kernel(const void* __restrict__ pos,
                                                  int* __restrict__ nbr,
                                                  const int* __restrict__ dfl) {
  __shared__ float px[1024], py[1024], pz[1024];
  const bool f32 = (*dfl != 0);
  int t = threadIdx.x;
  int b = blockIdx.y;
  int base = b << 10;
  for (int j = t; j < 1024; j += 256) {
    size_t pidx = (size_t)(base + j) * 3;
    px[j] = ldf(pos, pidx, f32);
    py[j] = ldf(pos, pidx + 1, f32);
    pz[j] = ldf(pos, pidx + 2, f32);
  }
  __syncthreads();
  int q = blockIdx.x * 256 + t;
  float qx = px[q], qy = py[q], qz = pz[q];
  float bd[20];
  int bi[20];
#pragma unroll
  for (int k = 0; k < 20; ++k) { bd[k] = 3.0e38f; bi[k] = 0; }
  for (int j = 0; j < 1024; ++j) {
    // exact fp32, no FMA contraction, same add order as reference sum(-1)
    float dx = qx - px[j], dy = qy - py[j], dz = qz - pz[j];
    float d = __fadd_rn(__fadd_rn(__fmul_rn(dx, dx), __fmul_rn(dy, dy)),
                        __fmul_rn(dz, dz));
    if (j != q && d < bd[19]) {
#pragma unroll
      for (int k = 19; k >= 0; --k) {
        float prev = (k > 0) ? bd[k - 1] : -1.0f;
        int previ = (k > 0) ? bi[k - 1] : 0;
        if (prev > d) { bd[k] = prev; bi[k] = previ; }
        else          { bd[k] = d;    bi[k] = j;     break; }
      }
    }
  }
  int obase = (base + q) * 20;
#pragma unroll
  for (int k = 0; k < 20; ++k) nbr[obase + k] = bi[k];
}

// ---------------- unified MFMA KAN layer (L=1,2,3) --------------------------
// M-tile 256 rows, N-tile NT. A = Fourier features (fp16, on the fly),
// B = ct[o][f] fp16, fp32 MFMA accumulate, + bias.
// In/out: L1 in pos(ext) out f32 ; L2 in f32 out fp16 ; L3 in f32 out f32.
template <int L>
__global__ __launch_bounds__(256) void kan_kernel(
    const void* __restrict__ in_, const int* __restrict__ nbr,
    const void* __restrict__ pos, const u16* __restrict__ ct,
    const void* __restrict__ bias, void* __restrict__ out_,
    const int* __restrict__ dfl) {
  constexpr int W    = (L == 1) ? 3  : (L == 2) ? 16  : 32;
  constexpr int S    = (L == 1) ? 3  : (L == 2) ? 8   : 16;
  constexpr int DIN  = (L == 1) ? 6  : (L == 2) ? 64  : 128;
  constexpr int DOUT = (L == 1) ? 64 : (L == 2) ? 128 : 1024;
  constexpr int NT   = (L == 1) ? 64 : 128;
  constexpr int NW   = (DIN - W) / S + 1;
  constexpr int NPAIR = NW * W * 5;                 // (angle,harmonic) pairs
  constexpr int KROW  = (L == 1) ? 64 : NPAIR * 2;  // ct row stride (padded L1)
  constexpr int NCH   = KROW / 32;
  constexpr int NB    = NT / 16;

  __shared__ u16 Abuf[256 * 40];   // [row][f] stride 40 fp16 (80B, 16B-aligned)
  __shared__ u16 Bbuf[NT * 40];    // [o][f]   stride 40 fp16
  __shared__ float hamS[W];

  const bool f32 = (*dfl != 0);
  const float* inF = (const float*)in_;
  const int t = threadIdx.x;
  if (t < W) hamS[t] = 0.54f - 0.46f * cospif(2.0f * (float)t / (float)(W - 1));
  const int tile = blockIdx.x;
  const int ncol0 = blockIdx.y * NT;
  const int lane = t & 63, wv = t >> 6;
  const int m16 = lane & 15, kb = lane >> 4;
  const int p = t & 15, esub = t >> 4;

  f32x4 acc[4][NB];
#pragma unroll
  for (int mb = 0; mb < 4; ++mb)
#pragma unroll
    for (int nb = 0; nb < NB; ++nb) {
      acc[mb][nb][0] = 0.f; acc[mb][nb][1] = 0.f;
      acc[mb][nb][2] = 0.f; acc[mb][nb][3] = 0.f;
    }
  __syncthreads();  // hamS ready

  for (int c = 0; c < NCH; ++c) {
    const int pg = c * 16 + p;
    const bool valid = (pg < NPAIR);
    const int gg = pg % 5, aa = pg / 5;
    const int i = aa % W, w = aa / W;
    const int hidx = S * w + i;
    const float kf = (float)(gg + 1);
    // ---- stage A: 16 rows per thread, one (angle,harmonic) pair each ----
#pragma unroll
    for (int j = 0; j < 16; ++j) {
      const int e = esub + j * 16;
      const int row = tile * 256 + e;
      u32 u = 0u;
      if (valid) {
        float v;
        if constexpr (L == 1) {
          const int pt = row / 20;
          const int cloud = pt >> 10, ci = pt & 1023;
          const int cb = cloud << 10;
          if (aa < 3) {
            v = ldf(pos, (size_t)(cb + ci) * 3 + aa, f32);
          } else {
            const int jl = nbr[row];
            const int cc = aa - 3;
            v = ldf(pos, (size_t)(cb + jl) * 3 + cc, f32) -
                ldf(pos, (size_t)(cb + ci) * 3 + cc, f32);
          }
        } else {
          v = inF[(size_t)row * DIN + hidx];
        }
        const float arg = (v * hamS[i]) * kf;   // radians, like reference
        const float cs = __cosf(arg), sn = __sinf(arg);
        u = (u32)f2h(cs) | ((u32)f2h(sn) << 16);  // f even=cos, odd=sin
      }
      *(u32*)((char*)Abuf + e * 80 + p * 4) = u;
    }
    // ---- stage B: full 64B per row per chunk (4x uint4 per row) ----
    for (int s = t; s < NT * 4; s += 256) {
      const int o = s >> 2, qf = s & 3;
      const uint4 sv = *(const uint4*)((const char*)ct +
          ((size_t)(ncol0 + o) * KROW + c * 32 + qf * 8) * 2);
      *(uint4*)((char*)Bbuf + o * 80 + qf * 16) = sv;
    }
    __syncthreads();
    // ---- MFMA: wave wv owns m-blocks wv*4..wv*4+3, all NB n-blocks ----
    half8 af[4];
#pragma unroll
    for (int mb = 0; mb < 4; ++mb)
      af[mb] = *(const half8*)((const char*)Abuf +
                               ((wv * 4 + mb) * 16 + m16) * 80 + kb * 16);
#pragma unroll
    for (int nb = 0; nb < NB; ++nb) {
      const half8 bv = *(const half8*)((const char*)Bbuf +
                                       (nb * 16 + m16) * 80 + kb * 16);
#pragma unroll
      for (int mb = 0; mb < 4; ++mb)
        acc[mb][nb] = __builtin_amdgcn_mfma_f32_16x16x32_f16(
            af[mb], bv, acc[mb][nb], 0, 0, 0);
    }
    __syncthreads();
  }
  // ---- epilogue: D row=(lane>>4)*4+r, col=lane&15 ; + bias ----
#pragma unroll
  for (int mb = 0; mb < 4; ++mb) {
    const int row = tile * 256 + (wv * 4 + mb) * 16 + kb * 4;
#pragma unroll
    for (int nb = 0; nb < NB; ++nb) {
      const int col = ncol0 + nb * 16 + m16;
      const float bsv = ldf(bias, col, f32);
#pragma unroll
      for (int r = 0; r < 4; ++r) {
        const float ov = acc[mb][nb][r] + bsv;
        if constexpr (L == 2)
          ((u16*)out_)[(size_t)(row + r) * DOUT + col] = f2h(ov);
        else
          ((float*)out_)[(size_t)(row + r) * DOUT + col] = ov;
      }
    }
  }
}

// ---------------- max over K=20 neighbors (fp16 in, f32 out) ----------------
__global__ void maxk_kernel(const u16* __restrict__ h2, float* __restrict__ x1) {
  int id = blockIdx.x * 256 + threadIdx.x;  // 8192*128 total
  int pcol = id & 127, pt = id >> 7;
  const u16* hp = h2 + (size_t)pt * 2560 + pcol;
  float m = -3.0e38f;
#pragma unroll
  for (int kk = 0; kk < 20; ++kk) m = fmaxf(m, h2f(hp[kk * 128]));
  x1[(size_t)pt * 128 + pcol] = m;
}

// ---------------- segment max + mean (equal clouds of 1024) -----------------
__global__ void seg_kernel(const float* __restrict__ x, float* __restrict__ xg) {
  int id = blockIdx.x * 256 + threadIdx.x;  // 8192 total
  int b = id >> 10, cc = id & 1023;
  const float* xp = x + ((size_t)(b << 10)) * 1024 + cc;
  float m = -3.0e38f, s = 0.f;
  for (int r = 0; r < 1024; ++r) {
    float v = xp[(size_t)r * 1024];
    m = fmaxf(m, v);
    s += v;
  }
  xg[b * 2048 + cc] = m;
  xg[b * 2048 + 1024 + cc] = s * (1.0f / 1024.0f);
}

// ---------------- layer 4 partials: one WG per (window, batch) --------------
// part layout: [b][w][slice(6)][o(40)]  (no races)
__global__ __launch_bounds__(256) void l4_kernel(const float* __restrict__ xg,
                                                 const float* __restrict__ c4t,
                                                 float* __restrict__ part) {
  __shared__ float F[2560];
  const int t = threadIdx.x;
  const int w = blockIdx.x, b = blockIdx.y;
  const float xv = xg[b * 2048 + w * 128 + t];
  const float hm = 0.54f - 0.46f * cospif(2.0f * (float)t / 255.0f);
  const float aa = xv * hm;
#pragma unroll
  for (int gg = 0; gg < 5; ++gg) {
    const float arg = aa * (float)(gg + 1);
    F[t * 10 + gg * 2] = __cosf(arg);
    F[t * 10 + gg * 2 + 1] = __sinf(arg);
  }
  __syncthreads();
  if (t < 240) {
    const int o = t % 40, s = t / 40;
    const int f0 = s * 432;
    const int f1 = (f0 + 432 < 2560) ? (f0 + 432) : 2560;
    const float* cp = c4t + (size_t)o * 38400 + w * 2560;
    float acc = 0.f;
    for (int f = f0; f < f1; f += 4) {
      const float4 cv = *(const float4*)&cp[f];
      const float4 fa = *(const float4*)&F[f];
      acc += fa.x * cv.x + fa.y * cv.y + fa.z * cv.z + fa.w * cv.w;
    }
    part[((b * 15 + w) * 6 + s) * 40 + o] = acc;
  }
}

__global__ void outred_kernel(const float* __restrict__ part,
                              const void* __restrict__ b4,
                              void* __restrict__ outp,
                              const int* __restrict__ dfl) {
  int t = threadIdx.x;
  if (t >= 320) return;
  const bool f32 = (*dfl != 0);
  int b = t / 40, o = t % 40;
  float s = ldf(b4, o, f32);
  for (int w = 0; w < 15; ++w)
#pragma unroll
    for (int sl = 0; sl < 6; ++sl)
      s += part[((b * 15 + w) * 6 + sl) * 40 + o];
  if (f32) ((float*)outp)[t] = s;
  else     ((u16*)outp)[t] = f2bfr(s);
}

// ---------------------------------------------------------------------------
extern "C" void kernel_launch(void* const* d_in, const int* in_sizes, int n_in,
                              void* d_out, int out_size, void* d_ws,
                              size_t ws_size, hipStream_t stream) {
  (void)in_sizes; (void)n_in; (void)out_size; (void)ws_size;
  const void* pos = d_in[0];
  // d_in[1] = batch (int32) -- clouds are sorted equal-size, used implicitly
  const void* c1 = d_in[2];
  const void* b1 = d_in[3];
  const void* c2 = d_in[4];
  const void* b2 = d_in[5];
  const void* c3 = d_in[6];
  const void* b3 = d_in[7];
  const void* c4 = d_in[8];
  const void* b4 = d_in[9];

  char* ws = (char*)d_ws;
  int* nbr   = (int*)(ws + NBR_OFF);
  int* flag  = (int*)(ws + FLAG_OFF);
  float* xg  = (float*)(ws + XG_OFF);
  float* l4p = (float*)(ws + L4P_OFF);
  u16* c1t   = (u16*)(ws + C1T_OFF);
  u16* c2t   = (u16*)(ws + C2T_OFF);
  u16* c3t   = (u16*)(ws + C3T_OFF);
  float* c4t = (float*)(ws + C4T_OFF);
  float* x1  = (float*)(ws + X1_OFF);
  float* h1  = (float*)(ws + H1_OFF);
  float* x   = (float*)(ws + X_OFF);
  u16* h2    = (u16*)(ws + H2_OFF);

  detect_kernel<<<1, 64, 0, stream>>>(pos, flag);

  tkan_kernel<<<16, 256, 0, stream>>>(c1, c1t, 64, 2, 3, 64 * 64, 64, 0, flag);
  tkan_kernel<<<560, 256, 0, stream>>>(c2, c2t, 128, 7, 16, 128 * 1120, 1120, 0, flag);
  tkan_kernel<<<8960, 256, 0, stream>>>(c3, c3t, 1024, 7, 32, 1024 * 2240, 2240, 0, flag);
  tkan_kernel<<<6000, 256, 0, stream>>>(c4, c4t, 40, 15, 256, 40 * 38400, 38400, 1, flag);

  knn_kernel<<<dim3(4, 8), 256, 0, stream>>>(pos, nbr, flag);

  kan_kernel<1><<<640, 256, 0, stream>>>(nullptr, nbr, pos, c1t, b1, h1, flag);
  kan_kernel<2><<<640, 256, 0, stream>>>(h1, nullptr, nullptr, c2t, b2, h2, flag);
  maxk_kernel<<<4096, 256, 0, stream>>>(h2, x1);
  kan_kernel<3><<<dim3(32, 8), 256, 0, stream>>>(x1, nullptr, nullptr, c3t, b3, x, flag);

  seg_kernel<<<32, 256, 0, stream>>>(x, xg);
  l4_kernel<<<dim3(15, 8), 256, 0, stream>>>(xg, c4t, l4p);
  outred_kernel<<<1, 320, 0, stream>>>(l4p, b4, d_out, flag);
}

// Round 8
// 560.243 us; speedup vs baseline: 6.9008x; 6.9008x over previous
//
#include <hip/hip_runtime.h>

// ---------------------------------------------------------------------------
// STFT-Fourier-KAN DGCNN on MI355X.
// R7: PASS (absmax 0.0156). Profile: knn_kernel = 87% of 3866 us, VGPR=40,
// occupancy 1.3% -> top-k arrays spilled to scratch + only 128 waves total.
// R8: kNN rewritten as one-wave-per-query: LDS-staged cloud, 16 candidates
// per lane, u64 (dist_bits<<32 | idx) keys, 20x wave-wide min-extract via
// butterfly shuffles. All selection state in registers w/ compile-time
// indices. 8192 waves -> full occupancy. Rest of pipeline unchanged.
// ---------------------------------------------------------------------------

typedef unsigned short u16;
typedef unsigned int   u32;
typedef unsigned long long u64;
typedef __attribute__((ext_vector_type(8))) _Float16 half8;
typedef __attribute__((ext_vector_type(4))) float f32x4;

__device__ __forceinline__ float bf2f(u16 u) {
  u32 v = ((u32)u) << 16;
  return __uint_as_float(v);
}
__device__ __forceinline__ u16 f2bfr(float f) {  // bf16 round-to-nearest-even
  u32 x = __float_as_uint(f);
  u32 r = x + 0x7FFFu + ((x >> 16) & 1u);
  return (u16)(r >> 16);
}
__device__ __forceinline__ u16 f2h(float f) {    // fp16 RTN bits
  _Float16 h = (_Float16)f;
  u16 r;
  __builtin_memcpy(&r, &h, 2);
  return r;
}
__device__ __forceinline__ float h2f(u16 u) {
  _Float16 h;
  __builtin_memcpy(&h, &u, 2);
  return (float)h;
}
// dtype-dispatched external load (flag wave-uniform -> scalar branch)
__device__ __forceinline__ float ldf(const void* p, size_t i, bool f32) {
  return f32 ? ((const float*)p)[i] : bf2f(((const u16*)p)[i]);
}
__device__ __forceinline__ u64 minu64(u64 a, u64 b) { return a < b ? a : b; }

// ---------------- workspace layout (bytes) ----------------
#define NBR_OFF   ((size_t)0)                       // int32 [163840]       655,360
#define FLAG_OFF  ((size_t)917504)                  // int32 [1]
#define XG_OFF    ((size_t)(1u << 20))              // f32 [8][2048]         65,536
#define L4P_OFF   (((size_t)(1u << 20)) + 131072)   // f32 [8][15][240]     115,200
#define C1T_OFF   (((size_t)(1u << 20)) + 524288)   // fp16 [64][64]          8,192
#define C2T_OFF   (((size_t)(1u << 20)) + 589824)   // fp16 [128][1120]     286,720
#define C3T_OFF   ((size_t)(2u << 20))              // fp16 [1024][2240]  4,587,520
#define C4T_OFF   ((size_t)(7u << 20))              // f32  [40][38400]   6,144,000
#define X1_OFF    ((size_t)(14u << 20))             // f32 [8192][128]    4,194,304
#define H1_OFF    ((size_t)(19u << 20))             // f32 [163840][64]  41,943,040
#define X_OFF     ((size_t)(19u << 20))             // f32 [8192][1024]  (overlaps dead h1)
#define H2_OFF    ((size_t)(61u << 20))             // fp16 [163840][128] 41,943,040
// peak ~103 MB

// ---------------- dtype detector -------------------------------------------
__global__ void detect_kernel(const void* __restrict__ pos,
                              int* __restrict__ flag) {
  int t = threadIdx.x;  // 64 threads
  float a = fabsf(((const float*)pos)[t]);
  bool ok = (a > 1.0e-3f && a < 100.0f);
  unsigned long long m = __ballot(ok);
  if (t == 0) *flag = (__popcll(m) >= 32) ? 1 : 0;  // 1 = fp32 externals
}

// ---------------- coeff transpose: c[part][o][w][i][g] -> ct[o][f] ----------
// f = ((w*W+i)*5 + g)*2 + part ; pad f>=Kt with zeros (layer1 pads 60->64)
// outf32: write fp32 (layer 4) else fp16 bits
__global__ void tkan_kernel(const void* __restrict__ src, void* __restrict__ dst,
                            int dout, int nw, int W, int total, int KPAD,
                            int outf32, const int* __restrict__ dfl) {
  int id = blockIdx.x * 256 + threadIdx.x;
  if (id >= total) return;
  const bool f32 = (*dfl != 0);
  int o = id / KPAD, f = id % KPAD;
  int Kt = nw * W * 10;
  float v = 0.f;
  if (f < Kt) {
    int part = f & 1, q = f >> 1;
    int gg = q % 5, a2 = q / 5;
    int i = a2 % W, w = a2 / W;
    int OS = nw * W * 5;
    size_t sidx = (size_t)part * (dout * OS) + (size_t)o * OS + w * (W * 5) + i * 5 + gg;
    v = ldf(src, sidx, f32);
  }
  if (outf32) ((float*)dst)[id] = v;
  else        ((u16*)dst)[id] = f2h(v);
}

// ---------------- brute-force kNN: one wave per query -----------------------
// Lane l holds candidates j = s*64+l (s=0..15) as u64 keys (dist<<32|idx);
// 20 rounds of {16-way register min, 6-step butterfly wave min, invalidate}.
// Tie semantics: smallest distance, then smallest index == stable lax.top_k.
__global__ __launch_bounds__(256) void knn_kernel(const void* __restrict__ pos,
                                                  int* __restrict__ nbr,
                                                  const int* __restrict__ dfl) {
  __shared__ float px[1024], py[1024], pz[1024];
  const bool f32 = (*dfl != 0);
  const int t = threadIdx.x;
  const int b = blockIdx.y;
  const int base = b << 10;
  for (int j = t; j < 1024; j += 256) {
    size_t pidx = (size_t)(base + j) * 3;
    px[j] = ldf(pos, pidx, f32);
    py[j] = ldf(pos, pidx + 1, f32);
    pz[j] = ldf(pos, pidx + 2, f32);
  }
  __syncthreads();
  const int wv = t >> 6, lane = t & 63;
  const int q = blockIdx.x * 4 + wv;
  const float qx = px[q], qy = py[q], qz = pz[q];
  u64 key[16];
#pragma unroll
  for (int s = 0; s < 16; ++s) {
    const int j = s * 64 + lane;
    // exact fp32, no FMA contraction, same add order as reference sum(-1)
    float dx = qx - px[j], dy = qy - py[j], dz = qz - pz[j];
    float d = __fadd_rn(__fadd_rn(__fmul_rn(dx, dx), __fmul_rn(dy, dy)),
                        __fmul_rn(dz, dz));
    key[s] = (j == q) ? ~0ull
                      : ((((u64)__float_as_uint(d)) << 32) | (u32)j);
  }
  const int obase = (base + q) * 20;
  for (int k = 0; k < 20; ++k) {
    u64 m = key[0];
#pragma unroll
    for (int s = 1; s < 16; ++s) m = minu64(m, key[s]);
#pragma unroll
    for (int off = 32; off >= 1; off >>= 1) {
      u32 lo = (u32)m, hi = (u32)(m >> 32);
      lo = __shfl_xor(lo, off, 64);
      hi = __shfl_xor(hi, off, 64);
      m = minu64(m, (((u64)hi) << 32) | lo);
    }
    if (lane == 0) nbr[obase + k] = (int)(u32)m;
#pragma unroll
    for (int s = 0; s < 16; ++s)
      if (key[s] == m) key[s] = ~0ull;  // idx embedded -> unique, safe
  }
}

// ---------------- unified MFMA KAN layer (L=1,2,3) --------------------------
// M-tile 256 rows, N-tile NT. A = Fourier features (fp16, on the fly),
// B = ct[o][f] fp16, fp32 MFMA accumulate, + bias.
// In/out: L1 in pos(ext) out f32 ; L2 in f32 out fp16 ; L3 in f32 out f32.
template <int L>
__global__ __launch_bounds__(256) void kan_kernel(
    const void* __restrict__ in_, const int* __restrict__ nbr,
    const void* __restrict__ pos, const u16* __restrict__ ct,
    const void* __restrict__ bias, void* __restrict__ out_,
    const int* __restrict__ dfl) {
  constexpr int W    = (L == 1) ? 3  : (L == 2) ? 16  : 32;
  constexpr int S    = (L == 1) ? 3  : (L == 2) ? 8   : 16;
  constexpr int DIN  = (L == 1) ? 6  : (L == 2) ? 64  : 128;
  constexpr int DOUT = (L == 1) ? 64 : (L == 2) ? 128 : 1024;
  constexpr int NT   = (L == 1) ? 64 : 128;
  constexpr int NW   = (DIN - W) / S + 1;
  constexpr int NPAIR = NW * W * 5;                 // (angle,harmonic) pairs
  constexpr int KROW  = (L == 1) ? 64 : NPAIR * 2;  // ct row stride (padded L1)
  constexpr int NCH   = KROW / 32;
  constexpr int NB    = NT / 16;

  __shared__ u16 Abuf[256 * 40];   // [row][f] stride 40 fp16 (80B, 16B-aligned)
  __shared__ u16 Bbuf[NT * 40];    // [o][f]   stride 40 fp16
  __shared__ float hamS[W];

  const bool f32 = (*dfl != 0);
  const float* inF = (const float*)in_;
  const int t = threadIdx.x;
  if (t < W) hamS[t] = 0.54f - 0.46f * cospif(2.0f * (float)t / (float)(W - 1));
  const int tile = blockIdx.x;
  const int ncol0 = blockIdx.y * NT;
  const int lane = t & 63, wv = t >> 6;
  const int m16 = lane & 15, kb = lane >> 4;
  const int p = t & 15, esub = t >> 4;

  f32x4 acc[4][NB];
#pragma unroll
  for (int mb = 0; mb < 4; ++mb)
#pragma unroll
    for (int nb = 0; nb < NB; ++nb) {
      acc[mb][nb][0] = 0.f; acc[mb][nb][1] = 0.f;
      acc[mb][nb][2] = 0.f; acc[mb][nb][3] = 0.f;
    }
  __syncthreads();  // hamS ready

  for (int c = 0; c < NCH; ++c) {
    const int pg = c * 16 + p;
    const bool valid = (pg < NPAIR);
    const int gg = pg % 5, aa = pg / 5;
    const int i = aa % W, w = aa / W;
    const int hidx = S * w + i;
    const float kf = (float)(gg + 1);
    // ---- stage A: 16 rows per thread, one (angle,harmonic) pair each ----
#pragma unroll
    for (int j = 0; j < 16; ++j) {
      const int e = esub + j * 16;
      const int row = tile * 256 + e;
      u32 u = 0u;
      if (valid) {
        float v;
        if constexpr (L == 1) {
          const int pt = row / 20;
          const int cloud = pt >> 10, ci = pt & 1023;
          const int cb = cloud << 10;
          if (aa < 3) {
            v = ldf(pos, (size_t)(cb + ci) * 3 + aa, f32);
          } else {
            const int jl = nbr[row];
            const int cc = aa - 3;
            v = ldf(pos, (size_t)(cb + jl) * 3 + cc, f32) -
                ldf(pos, (size_t)(cb + ci) * 3 + cc, f32);
          }
        } else {
          v = inF[(size_t)row * DIN + hidx];
        }
        const float arg = (v * hamS[i]) * kf;   // radians, like reference
        const float cs = __cosf(arg), sn = __sinf(arg);
        u = (u32)f2h(cs) | ((u32)f2h(sn) << 16);  // f even=cos, odd=sin
      }
      *(u32*)((char*)Abuf + e * 80 + p * 4) = u;
    }
    // ---- stage B: full 64B per row per chunk (4x uint4 per row) ----
    for (int s = t; s < NT * 4; s += 256) {
      const int o = s >> 2, qf = s & 3;
      const uint4 sv = *(const uint4*)((const char*)ct +
          ((size_t)(ncol0 + o) * KROW + c * 32 + qf * 8) * 2);
      *(uint4*)((char*)Bbuf + o * 80 + qf * 16) = sv;
    }
    __syncthreads();
    // ---- MFMA: wave wv owns m-blocks wv*4..wv*4+3, all NB n-blocks ----
    half8 af[4];
#pragma unroll
    for (int mb = 0; mb < 4; ++mb)
      af[mb] = *(const half8*)((const char*)Abuf +
                               ((wv * 4 + mb) * 16 + m16) * 80 + kb * 16);
#pragma unroll
    for (int nb = 0; nb < NB; ++nb) {
      const half8 bv = *(const half8*)((const char*)Bbuf +
                                       (nb * 16 + m16) * 80 + kb * 16);
#pragma unroll
      for (int mb = 0; mb < 4; ++mb)
        acc[mb][nb] = __builtin_amdgcn_mfma_f32_16x16x32_f16(
            af[mb], bv, acc[mb][nb], 0, 0, 0);
    }
    __syncthreads();
  }
  // ---- epilogue: D row=(lane>>4)*4+r, col=lane&15 ; + bias ----
#pragma unroll
  for (int mb = 0; mb < 4; ++mb) {
    const int row = tile * 256 + (wv * 4 + mb) * 16 + kb * 4;
#pragma unroll
    for (int nb = 0; nb < NB; ++nb) {
      const int col = ncol0 + nb * 16 + m16;
      const float bsv = ldf(bias, col, f32);
#pragma unroll
      for (int r = 0; r < 4; ++r) {
        const float ov = acc[mb][nb][r] + bsv;
        if constexpr (L == 2)
          ((u16*)out_)[(size_t)(row + r) * DOUT + col] = f2h(ov);
        else
          ((float*)out_)[(size_t)(row + r) * DOUT + col] = ov;
      }
    }
  }
}

// ---------------- max over K=20 neighbors (fp16 in, f32 out) ----------------
__global__ void maxk_kernel(const u16* __restrict__ h2, float* __restrict__ x1) {
  int id = blockIdx.x * 256 + threadIdx.x;  // 8192*128 total
  int pcol = id & 127, pt = id >> 7;
  const u16* hp = h2 + (size_t)pt * 2560 + pcol;
  float m = -3.0e38f;
#pragma unroll
  for (int kk = 0; kk < 20; ++kk) m = fmaxf(m, h2f(hp[kk * 128]));
  x1[(size_t)pt * 128 + pcol] = m;
}

// ---------------- segment max + mean (equal clouds of 1024) -----------------
__global__ void seg_kernel(const float* __restrict__ x, float* __restrict__ xg) {
  int id = blockIdx.x * 256 + threadIdx.x;  // 8192 total
  int b = id >> 10, cc = id & 1023;
  const float* xp = x + ((size_t)(b << 10)) * 1024 + cc;
  float m = -3.0e38f, s = 0.f;
  for (int r = 0; r < 1024; ++r) {
    float v = xp[(size_t)r * 1024];
    m = fmaxf(m, v);
    s += v;
  }
  xg[b * 2048 + cc] = m;
  xg[b * 2048 + 1024 + cc] = s * (1.0f / 1024.0f);
}

// ---------------- layer 4 partials: one WG per (window, batch) --------------
// part layout: [b][w][slice(6)][o(40)]  (no races)
__global__ __launch_bounds__(256) void l4_kernel(const float* __restrict__ xg,
                                                 const float* __restrict__ c4t,
                                                 float* __restrict__ part) {
  __shared__ float F[2560];
  const int t = threadIdx.x;
  const int w = blockIdx.x, b = blockIdx.y;
  const float xv = xg[b * 2048 + w * 128 + t];
  const float hm = 0.54f - 0.46f * cospif(2.0f * (float)t / 255.0f);
  const float aa = xv * hm;
#pragma unroll
  for (int gg = 0; gg < 5; ++gg) {
    const float arg = aa * (float)(gg + 1);
    F[t * 10 + gg * 2] = __cosf(arg);
    F[t * 10 + gg * 2 + 1] = __sinf(arg);
  }
  __syncthreads();
  if (t < 240) {
    const int o = t % 40, s = t / 40;
    const int f0 = s * 432;
    const int f1 = (f0 + 432 < 2560) ? (f0 + 432) : 2560;
    const float* cp = c4t + (size_t)o * 38400 + w * 2560;
    float acc = 0.f;
    for (int f = f0; f < f1; f += 4) {
      const float4 cv = *(const float4*)&cp[f];
      const float4 fa = *(const float4*)&F[f];
      acc += fa.x * cv.x + fa.y * cv.y + fa.z * cv.z + fa.w * cv.w;
    }
    part[((b * 15 + w) * 6 + s) * 40 + o] = acc;
  }
}

__global__ void outred_kernel(const float* __restrict__ part,
                              const void* __restrict__ b4,
                              void* __restrict__ outp,
                              const int* __restrict__ dfl) {
  int t = threadIdx.x;
  if (t >= 320) return;
  const bool f32 = (*dfl != 0);
  int b = t / 40, o = t % 40;
  float s = ldf(b4, o, f32);
  for (int w = 0; w < 15; ++w)
#pragma unroll
    for (int sl = 0; sl < 6; ++sl)
      s += part[((b * 15 + w) * 6 + sl) * 40 + o];
  if (f32) ((float*)outp)[t] = s;
  else     ((u16*)outp)[t] = f2bfr(s);
}

// ---------------------------------------------------------------------------
extern "C" void kernel_launch(void* const* d_in, const int* in_sizes, int n_in,
                              void* d_out, int out_size, void* d_ws,
                              size_t ws_size, hipStream_t stream) {
  (void)in_sizes; (void)n_in; (void)out_size; (void)ws_size;
  const void* pos = d_in[0];
  // d_in[1] = batch (int32) -- clouds are sorted equal-size, used implicitly
  const void* c1 = d_in[2];
  const void* b1 = d_in[3];
  const void* c2 = d_in[4];
  const void* b2 = d_in[5];
  const void* c3 = d_in[6];
  const void* b3 = d_in[7];
  const void* c4 = d_in[8];
  const void* b4 = d_in[9];

  char* ws = (char*)d_ws;
  int* nbr   = (int*)(ws + NBR_OFF);
  int* flag  = (int*)(ws + FLAG_OFF);
  float* xg  = (float*)(ws + XG_OFF);
  float* l4p = (float*)(ws + L4P_OFF);
  u16* c1t   = (u16*)(ws + C1T_OFF);
  u16* c2t   = (u16*)(ws + C2T_OFF);
  u16* c3t   = (u16*)(ws + C3T_OFF);
  float* c4t = (float*)(ws + C4T_OFF);
  float* x1  = (float*)(ws + X1_OFF);
  float* h1  = (float*)(ws + H1_OFF);
  float* x   = (float*)(ws + X_OFF);
  u16* h2    = (u16*)(ws + H2_OFF);

  detect_kernel<<<1, 64, 0, stream>>>(pos, flag);

  tkan_kernel<<<16, 256, 0, stream>>>(c1, c1t, 64, 2, 3, 64 * 64, 64, 0, flag);
  tkan_kernel<<<560, 256, 0, stream>>>(c2, c2t, 128, 7, 16, 128 * 1120, 1120, 0, flag);
  tkan_kernel<<<8960, 256, 0, stream>>>(c3, c3t, 1024, 7, 32, 1024 * 2240, 2240, 0, flag);
  tkan_kernel<<<6000, 256, 0, stream>>>(c4, c4t, 40, 15, 256, 40 * 38400, 38400, 1, flag);

  knn_kernel<<<dim3(256, 8), 256, 0, stream>>>(pos, nbr, flag);

  kan_kernel<1><<<640, 256, 0, stream>>>(nullptr, nbr, pos, c1t, b1, h1, flag);
  kan_kernel<2><<<640, 256, 0, stream>>>(h1, nullptr, nullptr, c2t, b2, h2, flag);
  maxk_kernel<<<4096, 256, 0, stream>>>(h2, x1);
  kan_kernel<3><<<dim3(32, 8), 256, 0, stream>>>(x1, nullptr, nullptr, c3t, b3, x, flag);

  seg_kernel<<<32, 256, 0, stream>>>(x, xg);
  l4_kernel<<<dim3(15, 8), 256, 0, stream>>>(xg, c4t, l4p);
  outred_kernel<<<1, 320, 0, stream>>>(l4p, b4, d_out, flag);
}